// Round 9
// baseline (165.569 us; speedup 1.0000x reference)
//
#include <hip/hip_runtime.h>

// ---------------------------------------------------------------------------
// Q_DenseLayer: BN-fold int8 affine -> ReLU -> per-tensor 8b quant ->
// int8 3x3 conv (MFMA i32_32x32x32_i8) -> per-tensor 8b requant.
// Shapes: x[32,512,32,32] f32, W[128,512,3,3] f32, out y[32,128,32,32] + s_out.
//
// R9: k_conv on 32x32x32 i8 MFMA (half the MFMA instrs, 4404-TOPS ceiling).
// Byte layouts of x2/wq are IDENTICAL to R6-R8 (16B unit = 16 consecutive
// channels; cdw = c/16 either way) -> only k_conv changed:
//   A: m=lane&31 -> w, khalf=lane>>5 -> k-half; addr (ci*2+khalf)*544+(m+kw)*16
//   B: n=lane&31 -> co; staged via global_load_lds, 36KB/j (1 ci32 per kv slot)
//   A row-dedup: 4 row loads per kw serve 6 (mt,kh) pairs.
//   (256,4): 4 blocks/CU (36KB LDS), ~118 VGPR fits 128 budget.
// C layout (HW-verified): col=lane&31=co, row=(reg&3)+8*(reg>>2)+4*khalf=w.
// Fixed ~95us harness overhead in timed window; controllable budget ~65us.
// ---------------------------------------------------------------------------

typedef int v4i  __attribute__((ext_vector_type(4)));
typedef int v16i __attribute__((ext_vector_type(16)));

// workspace byte offsets
#define WS_A1    64        // 512 f: A1_c = w_int*bn_sf/s_in
#define WS_B1    2112      // 512 f: B1_c = b_int*bn_sf
#define WS_WSC   4160      // 128 f
#define WS_XMX   4672      // 512 f: per-channel max(x)
#define WS_XMN   6720      // 512 f: per-channel min(x)
#define WS_WQ    8768      // 589824 i8: [tap][cdw32][co128][16]
#define WS_X2    598592    // 17825792 u8: [b][h][cdw32][w'34][16]
#define WS_ZROW  18424384  // 17408 u8 zero row
// ws_f[3] = s_act (k_xquant blk0), ws_u[1] = absmax(y) bits

__device__ __forceinline__ float wave_max(float m) {
#pragma unroll
    for (int off = 32; off; off >>= 1) m = fmaxf(m, __shfl_xor(m, off));
    return m;
}

// async global->LDS, 16B per lane: per-lane gsrc, wave-uniform LDS base
__device__ __forceinline__ void stage16(const char* g, char* s, int lane) {
#if defined(__has_builtin) && __has_builtin(__builtin_amdgcn_global_load_lds)
    __builtin_amdgcn_global_load_lds(
        (const __attribute__((address_space(1))) void*)g,
        (__attribute__((address_space(3))) void*)s, 16, 0, 0);
#else
    *(v4i*)(s + lane * 16) = *(const v4i*)g;
#endif
}

// ---- kernel 1: fused prep ---------------------------------------------------
// blocks 0..511:   per-channel x max/min (block c owns channel c)
// blocks 512..639: conv-weight quant (co = bid-512)
// block 640:       BN fold -> A1/B1
__global__ __launch_bounds__(512) void k_prep(
    const float* __restrict__ gamma, const float* __restrict__ beta,
    const float* __restrict__ mean,  const float* __restrict__ var,
    const float* __restrict__ asf,   const float* __restrict__ cw,
    const float4* __restrict__ x4,
    float* ws_f, unsigned* ws_u, float* __restrict__ wsc,
    signed char* __restrict__ wq) {
    int t = threadIdx.x;
    int bid = blockIdx.x;
    __shared__ float red[16];
    if (bid < 512) {
        int c = bid;
        float mx = -3.4e38f, mn = 3.4e38f;
#pragma unroll
        for (int r = 0; r < 16; ++r) {
            int bbb = r * 2 + (t >> 8);
            float4 v = x4[((size_t)(bbb * 512 + c)) * 256 + (t & 255)];
            mx = fmaxf(mx, fmaxf(fmaxf(v.x, v.y), fmaxf(v.z, v.w)));
            mn = fminf(mn, fminf(fminf(v.x, v.y), fminf(v.z, v.w)));
        }
        mx = wave_max(mx);
        mn = -wave_max(-mn);
        if ((t & 63) == 0) { red[t >> 6] = mx; red[8 + (t >> 6)] = mn; }
        __syncthreads();
        if (t == 0) {
            float M = red[0], N = red[8];
#pragma unroll
            for (int i = 1; i < 8; ++i) { M = fmaxf(M, red[i]); N = fminf(N, red[8 + i]); }
            ws_f[WS_XMX / 4 + c] = M;
            ws_f[WS_XMN / 4 + c] = N;
        }
    } else if (bid < 640) {
        int co = bid - 512;
        const float* w = cw + (size_t)co * 4608;
        float m = 0.f;
        for (int j = t; j < 4608; j += 512) m = fmaxf(m, fabsf(w[j]));
        m = wave_max(m);
        if ((t & 63) == 0) red[t >> 6] = m;
        __syncthreads();
        float mall = red[0];
#pragma unroll
        for (int i = 1; i < 8; ++i) mall = fmaxf(mall, red[i]);
        float sc = mall / 127.0f;
        if (t == 0) wsc[co] = sc;
        int cdw = t >> 4, cb = t & 15;  // channel dword-group, byte
#pragma unroll
        for (int tap = 0; tap < 9; ++tap) {
            float q = fminf(fmaxf(rintf(w[t * 9 + tap] / sc), -128.f), 127.f);
            wq[(((size_t)tap * 32 + cdw) * 128 + co) * 16 + cb] = (signed char)q;
        }
    } else {
        float wbn = gamma[t] / sqrtf(var[t] + 1e-5f);
        float bbn = beta[t] - mean[t] * wbn;
        float m = wave_max(fabsf(wbn));
        if ((t & 63) == 0) red[t >> 6] = m;
        __syncthreads();
        float mall = red[0];
#pragma unroll
        for (int i = 1; i < 8; ++i) mall = fmaxf(mall, red[i]);
        float ws_bn = mall / 127.0f;
        float s_in  = asf[0];
        float bn_sf = ws_bn * s_in;
        float wint  = fminf(fmaxf(rintf(wbn / ws_bn), -128.f), 127.f);
        float bint  = rintf(bbn / bn_sf);
        ws_f[WS_A1 / 4 + t] = wint * bn_sf / s_in;  // x1 = fmaf(x, A1, B1)
        ws_f[WS_B1 / 4 + t] = bint * bn_sf;
        if (t == 0) ws_u[1] = 0u;  // absmax(y) bits
    }
}

// ---- kernel 2: quantize x to int8 [cdw32][w'34][16] halo layout ------------
__global__ __launch_bounds__(256) void k_xquant(
    const float4* __restrict__ x4, float* __restrict__ ws_f,
    unsigned* __restrict__ x2u, unsigned* __restrict__ zrowu) {
    int bb = 31 - (blockIdx.x >> 5), h = blockIdx.x & 31;
    const float* A1 = ws_f + WS_A1 / 4;
    const float* B1 = ws_f + WS_B1 / 4;
    const float* XMX = ws_f + WS_XMX / 4;
    const float* XMN = ws_f + WS_XMN / 4;
    int t = threadIdx.x;

    // s_act from per-channel stats (exact: fma monotone in x, relu clamp >=0)
    __shared__ float sred[4];
    float cand = 0.f;
#pragma unroll
    for (int c0 = 0; c0 < 512; c0 += 256) {
        int c = c0 + t;
        float A = A1[c], B = B1[c];
        cand = fmaxf(cand, fmaxf(fmaf(XMX[c], A, B), fmaf(XMN[c], A, B)));
    }
    cand = wave_max(cand);
    if ((t & 63) == 0) sred[t >> 6] = cand;
    __syncthreads();
    float xm = fmaxf(fmaxf(sred[0], sred[1]), fmaxf(sred[2], sred[3]));
    float inv_sact = 127.0f / xm;
    if (blockIdx.x == 0 && t == 0) ws_f[3] = xm / 127.0f;  // s_act for k_conv

    size_t rowd = (size_t)(bb * 32 + h) * 4352;  // dwords per (b,h) row
    // zero halo columns w'=0,33
    {
        int p = t >> 3, side = (t >> 2) & 1, d = t & 3;
        x2u[rowd + (p * 34 + side * 33) * 4 + d] = 0u;
    }
    if (blockIdx.x < 17) {
        int idx = blockIdx.x * 256 + t;
        if (idx < 4352) zrowu[idx] = 0u;
    }

    __shared__ unsigned lds[512 * 9];  // [c][w4(8)] packed bytes, +1 pad

#pragma unroll
    for (int it = 0; it < 16; ++it) {
        int idx = it * 256 + t;
        int c = idx >> 3, f4 = idx & 7;
        float4 v = x4[((size_t)bb * 512 + c) * 256 + h * 8 + f4];
        float A = A1[c] * inv_sact, B = B1[c] * inv_sact;
        unsigned q0 = (unsigned)(int)fminf(rintf(fmaxf(fmaf(v.x, A, B), 0.f)), 127.f);
        unsigned q1 = (unsigned)(int)fminf(rintf(fmaxf(fmaf(v.y, A, B), 0.f)), 127.f);
        unsigned q2 = (unsigned)(int)fminf(rintf(fmaxf(fmaf(v.z, A, B), 0.f)), 127.f);
        unsigned q3 = (unsigned)(int)fminf(rintf(fmaxf(fmaf(v.w, A, B), 0.f)), 127.f);
        lds[c * 9 + f4] = q0 | (q1 << 8) | (q2 << 16) | (q3 << 24);
    }
    __syncthreads();

#pragma unroll
    for (int it = 0; it < 4; ++it) {
        int p = it * 8 + (t >> 5);   // cdw 0..31
        int s = (t >> 2) & 7;        // w4 group
        int k = t & 3;               // w = s*4+k, w' = w+1
        unsigned L[16];
#pragma unroll
        for (int j = 0; j < 16; ++j) L[j] = lds[(p * 16 + j) * 9 + s];
        uint4 o;
        unsigned* op = (unsigned*)&o;
#pragma unroll
        for (int d = 0; d < 4; ++d)
            op[d] = ((L[4 * d] >> (8 * k)) & 255u) |
                    (((L[4 * d + 1] >> (8 * k)) & 255u) << 8) |
                    (((L[4 * d + 2] >> (8 * k)) & 255u) << 16) |
                    (((L[4 * d + 3] >> (8 * k)) & 255u) << 24);
        *(uint4*)(x2u + rowd + (size_t)(p * 34 + s * 4 + 1 + k) * 4) = o;
    }
}

// ---- kernel 3: int8 3x3 conv via 32x32x32 MFMA, B staged through LDS -------
// block = 4 waves = (rp row-pairs) x (kv K-halves); wave tile 2 rows x 64 co.
// grid 512 XCD-swizzled; (256,4) => 4 blocks/CU, 36KB LDS.
__global__ __launch_bounds__(256, 4) void k_conv(
    const unsigned char* __restrict__ x2, const unsigned char* __restrict__ zrow,
    const signed char* __restrict__ wq,
    const float* __restrict__ wsc, const float* __restrict__ ws_f,
    unsigned* __restrict__ amaxy, float* __restrict__ y) {
    __shared__ char ldsb[36864];  // 2 kv slots x 18432 (9 tap x 2 kh x 1KB)
    int t = threadIdx.x;
    int lane = t & 63, wv = t >> 6;
    int kv = wv & 1, rp = wv >> 1;
    int m = lane & 31, khalf = lane >> 5;

    int bid = blockIdx.x;
    int tile = (bid & 7) * 64 + (bid >> 3);  // XCD swizzle, 64 tiles/XCD
    int ch = tile & 1;
    int rg = (tile >> 1) & 7;                // row-group of 4 rows
    int bb = tile >> 4;
    int co0 = ch * 64;
    int h0 = rg * 4 + rp * 2;                // this wave's first output row

    const unsigned char* xb = x2 + (size_t)bb * (32 * 17408);
    const char* rpt[4];
#pragma unroll
    for (int j = 0; j < 4; ++j) {
        int row = h0 - 1 + j;
        rpt[j] = (const char*)(((unsigned)row < 32u) ? (xb + (size_t)row * 17408) : zrow);
    }

    v16i acc[2][2];
#pragma unroll
    for (int i = 0; i < 2; ++i)
#pragma unroll
        for (int j = 0; j < 2; ++j)
#pragma unroll
            for (int e = 0; e < 16; ++e) acc[i][j][e] = 0;

    for (int j = 0; j < 8; ++j) {
        // stage B for ci32 = j (kv0 slot) and 8+j (kv1 slot): 36 x 1KB chunks
#pragma unroll
        for (int i = 0; i < 9; ++i) {
            int c = wv * 9 + i;
            int s = (c >= 18) ? 1 : 0;
            int r = c - s * 18;
            int tap = r >> 1, kh = r & 1;
            int ci = s * 8 + j;
            const char* g = (const char*)wq +
                (((size_t)(tap * 32 + ci * 2 + kh) * 128 + co0) * 16) + lane * 16;
            char* sdst = ldsb + s * 18432 + (tap * 2 + kh) * 1024;
            stage16(g, sdst, lane);
        }
        __syncthreads();

        int ci = kv * 8 + j;
        const char* bslot = ldsb + kv * 18432;
        int aoff = (ci * 2 + khalf) * 544 + m * 16;
#pragma unroll
        for (int kw = 0; kw < 3; ++kw) {
            v4i a[4];  // rows h0-1..h0+2, deduped across (mt,kh)
#pragma unroll
            for (int r = 0; r < 4; ++r)
                a[r] = *(const v4i*)(rpt[r] + aoff + kw * 16);
#pragma unroll
            for (int kh = 0; kh < 3; ++kh) {
                int tap = kh * 3 + kw;
#pragma unroll
                for (int nt = 0; nt < 2; ++nt) {
                    v4i bf = *(const v4i*)(bslot + (tap * 2 + khalf) * 1024 + (nt * 32 + m) * 16);
                    acc[0][nt] = __builtin_amdgcn_mfma_i32_32x32x32_i8(a[kh], bf, acc[0][nt], 0, 0, 0);
                    acc[1][nt] = __builtin_amdgcn_mfma_i32_32x32x32_i8(a[kh + 1], bf, acc[1][nt], 0, 0, 0);
                }
            }
        }
        __syncthreads();
    }

    // K-combine: kv=1 publishes (32KB, reuses stage LDS), kv=0 adds
    v4i* red = (v4i*)ldsb;
    if (kv == 1) {
#pragma unroll
        for (int mt = 0; mt < 2; ++mt)
#pragma unroll
            for (int nt = 0; nt < 2; ++nt) {
                const int* ap = (const int*)&acc[mt][nt];
#pragma unroll
                for (int g = 0; g < 4; ++g)
                    red[((((rp * 2 + mt) * 2 + nt) * 4 + g) << 6) + lane] = *(const v4i*)(ap + 4 * g);
            }
    }
    __syncthreads();
    if (kv == 0) {
        float s_act = ws_f[3];
        float mx = 0.f;
#pragma unroll
        for (int mt = 0; mt < 2; ++mt) {
            int row = h0 + mt;
#pragma unroll
            for (int nt = 0; nt < 2; ++nt) {
                int* ap = (int*)&acc[mt][nt];
                int co = co0 + nt * 32 + m;
                float sf = s_act * wsc[co];
                float* yb = y + ((size_t)(bb * 128 + co)) * 1024 + row * 32 + khalf * 4;
#pragma unroll
                for (int g = 0; g < 4; ++g) {
                    v4i p = red[((((rp * 2 + mt) * 2 + nt) * 4 + g) << 6) + lane];
                    float4 vv;
                    vv.x = (float)(ap[4 * g + 0] + p.x) * sf;
                    vv.y = (float)(ap[4 * g + 1] + p.y) * sf;
                    vv.z = (float)(ap[4 * g + 2] + p.z) * sf;
                    vv.w = (float)(ap[4 * g + 3] + p.w) * sf;
                    *(float4*)(yb + 8 * g) = vv;  // w = 8g + 4*khalf + 0..3
                    mx = fmaxf(mx, fmaxf(fmaxf(fabsf(vv.x), fabsf(vv.y)),
                                         fmaxf(fabsf(vv.z), fabsf(vv.w))));
                }
            }
        }
        mx = wave_max(mx);
        if (lane == 0) atomicMax(amaxy, __float_as_uint(mx));
    }
}

// ---- kernel 4: final requant in place + write s_out -----------------------
__global__ __launch_bounds__(256) void k_yquant(float* __restrict__ yout,
                                                const unsigned* __restrict__ ws_u) {
    float s_out = __uint_as_float(ws_u[1]) / 127.0f;
    float4* y4 = (float4*)yout;
    int stride = gridDim.x * blockDim.x;
    for (int i = blockIdx.x * blockDim.x + threadIdx.x; i < 1048576; i += stride) {
        float4 v = y4[i];
        v.x = fminf(fmaxf(rintf(v.x / s_out), -128.f), 127.f) * s_out;
        v.y = fminf(fmaxf(rintf(v.y / s_out), -128.f), 127.f) * s_out;
        v.z = fminf(fmaxf(rintf(v.z / s_out), -128.f), 127.f) * s_out;
        v.w = fminf(fmaxf(rintf(v.w / s_out), -128.f), 127.f) * s_out;
        y4[i] = v;
    }
    if (blockIdx.x == 0 && threadIdx.x == 0) yout[4194304] = s_out;
}

extern "C" void kernel_launch(void* const* d_in, const int* in_sizes, int n_in,
                              void* d_out, int out_size, void* d_ws, size_t ws_size,
                              hipStream_t stream) {
    const float* x     = (const float*)d_in[0];
    const float* asf   = (const float*)d_in[1];
    const float* gamma = (const float*)d_in[2];
    const float* beta  = (const float*)d_in[3];
    const float* mean  = (const float*)d_in[4];
    const float* var   = (const float*)d_in[5];
    const float* cw    = (const float*)d_in[6];

    float*    ws_f = (float*)d_ws;
    unsigned* ws_u = (unsigned*)d_ws;
    signed char*   wq   = (signed char*)d_ws + WS_WQ;
    unsigned char* x2   = (unsigned char*)d_ws + WS_X2;
    unsigned char* zrow = (unsigned char*)d_ws + WS_ZROW;
    float* y = (float*)d_out;

    k_prep<<<641, 512, 0, stream>>>(gamma, beta, mean, var, asf, cw,
                                    (const float4*)x, ws_f, ws_u,
                                    ws_f + WS_WSC / 4, wq);
    k_xquant<<<1024, 256, 0, stream>>>((const float4*)x, ws_f,
                                       (unsigned*)x2, (unsigned*)zrow);
    k_conv<<<512, 256, 0, stream>>>(x2, zrow, wq, ws_f + WS_WSC / 4,
                                    ws_f, ws_u + 1, y);
    k_yquant<<<1024, 256, 0, stream>>>(y, ws_u);
}